// Round 6
// baseline (240.712 us; speedup 1.0000x reference)
//
#include <hip/hip_runtime.h>
#include <math.h>

// Problem constants
#define Bn 4
#define Tn 2048
#define Cn 1024
#define Hn 16
#define HDn 64
#define Mn (Bn * Tn)  // 8192 tokens

typedef unsigned short u16;
typedef unsigned int u32;
typedef __attribute__((ext_vector_type(8))) short bf16x8;        // 8 bf16 = 4 VGPRs
typedef __attribute__((ext_vector_type(8))) unsigned short us8;  // 16B chunk
typedef __attribute__((ext_vector_type(4))) float f32x4;         // MFMA accumulator

__device__ __forceinline__ float b2f(u16 u) {
    return __uint_as_float(((u32)u) << 16);
}
__device__ __forceinline__ u16 f2b(float f) {
    u32 u = __float_as_uint(f);
    return (u16)((u + 0x7FFFu + ((u >> 16) & 1u)) >> 16);  // RNE
}
__device__ __forceinline__ u16 f2b_fast(float f) {
    return (u16)((__float_as_uint(f) + 0x8000u) >> 16);    // round-half-up
}

// XCD-grouped work id from flat block id (requires gridDim.x % 8 == 0).
__device__ __forceinline__ int xcd_work(int bid, int nwg) {
    return (bid & 7) * (nwg >> 3) + (bid >> 3);
}

// ---------------------------------------------------------------------------
// fp32 -> bf16 elementwise convert
// ---------------------------------------------------------------------------
__global__ __launch_bounds__(256) void cvt_f32_bf16_kernel(
    const float4* __restrict__ in, ushort4* __restrict__ out, int n4)
{
    int i = blockIdx.x * 256 + threadIdx.x;
    if (i < n4) {
        float4 v = in[i];
        ushort4 o;
        o.x = f2b(v.x); o.y = f2b(v.y); o.z = f2b(v.z); o.w = f2b(v.w);
        out[i] = o;
    }
}

// ---------------------------------------------------------------------------
// Transpose + convert: in [R,Cc] fp32 -> out [Cc,R] bf16. 32x32 LDS tiles.
// ---------------------------------------------------------------------------
__global__ __launch_bounds__(256) void transpose_cvt_kernel(
    const float* __restrict__ in, u16* __restrict__ out, int R, int Cc)
{
    __shared__ u16 t[32][33];
    const int c0 = blockIdx.x * 32, r0 = blockIdx.y * 32;
    const int tx = threadIdx.x & 31, ty = threadIdx.x >> 5;  // 32 x 8
    #pragma unroll
    for (int i = 0; i < 32; i += 8)
        t[ty + i][tx] = f2b(in[(size_t)(r0 + ty + i) * Cc + c0 + tx]);
    __syncthreads();
    #pragma unroll
    for (int i = 0; i < 32; i += 8)
        out[(size_t)(c0 + ty + i) * R + r0 + tx] = t[tx][ty + i];
}

// ---------------------------------------------------------------------------
// bf16 MFMA GEMM (m97 structure): Out[M,N] = A[M,K] @ BT[N,K]^T + bias[N]
// 128x128 tile, BK=32, 4 waves, global_load_lds width=16 staging, flat grid
// with XCD-grouped work remap.
// QKV_MODE: output cols >= 2048 (the V section) are written TRANSPOSED into
// vT[b][c][t] (b = row>>11, t = row&2047, c = col-2048). In C/D layout the 4
// acc regs are 4 consecutive rows (= consecutive t) -> one ushort4 store.
// ---------------------------------------------------------------------------
template <bool OUT_BF16, bool QKV_MODE>
__global__ __launch_bounds__(256) void gemm_bf16_kernel(
    const u16* __restrict__ A, const u16* __restrict__ BT,
    const float* __restrict__ bias,
    u16* __restrict__ outb, float* __restrict__ outf, u16* __restrict__ vTout,
    int N, int K, int nx)
{
    __shared__ u16 Al[128 * 32];
    __shared__ u16 Bl[128 * 32];

    const int tid = threadIdx.x;
    const int workid = xcd_work(blockIdx.x, gridDim.x);
    const int brow = (workid / nx) * 128;
    const int bcol = (workid % nx) * 128;
    const int w  = tid >> 6;
    const int wr = w >> 1, wc = w & 1;
    const int l  = tid & 63;
    const int lr = l & 15;
    const int lk = (l >> 4) << 3;

    f32x4 acc[4][4];
    #pragma unroll
    for (int m = 0; m < 4; ++m)
        #pragma unroll
        for (int n = 0; n < 4; ++n) acc[m][n] = (f32x4){0.f, 0.f, 0.f, 0.f};

    for (int k0 = 0; k0 < K; k0 += 32) {
        __syncthreads();  // protect prior iteration's fragment reads
        #pragma unroll
        for (int i = 0; i < 2; ++i) {
            const int c   = i * 256 + tid;    // chunk 0..511
            const int row = c >> 2;           // 0..127
            const int col = (c & 3) << 3;     // 0,8,16,24
            __builtin_amdgcn_global_load_lds(
                (const __attribute__((address_space(1))) u32*)
                    &A[(size_t)(brow + row) * K + k0 + col],
                (__attribute__((address_space(3))) u32*)
                    &Al[(size_t)(i * 256 + (tid & 192)) * 8],
                16, 0, 0);
            __builtin_amdgcn_global_load_lds(
                (const __attribute__((address_space(1))) u32*)
                    &BT[(size_t)(bcol + row) * K + k0 + col],
                (__attribute__((address_space(3))) u32*)
                    &Bl[(size_t)(i * 256 + (tid & 192)) * 8],
                16, 0, 0);
        }
        __syncthreads();

        bf16x8 a[4], b[4];
        #pragma unroll
        for (int m = 0; m < 4; ++m)
            a[m] = *(const bf16x8*)&Al[(wr * 64 + m * 16 + lr) * 32 + lk];
        #pragma unroll
        for (int n = 0; n < 4; ++n)
            b[n] = *(const bf16x8*)&Bl[(wc * 64 + n * 16 + lr) * 32 + lk];

        __builtin_amdgcn_s_setprio(1);
        #pragma unroll
        for (int m = 0; m < 4; ++m)
            #pragma unroll
            for (int n = 0; n < 4; ++n)
                acc[m][n] = __builtin_amdgcn_mfma_f32_16x16x32_bf16(
                    a[m], b[n], acc[m][n], 0, 0, 0);
        __builtin_amdgcn_s_setprio(0);
    }

    // Epilogue. C/D layout: col = lane&15, row = (lane>>4)*4 + reg.
    const int orow0 = brow + wr * 64 + ((l >> 4) << 2);
    const int ocol0 = bcol + wc * 64 + lr;
    if (QKV_MODE && bcol >= 2048) {
        // V section -> vT[b][c][t]; 4 acc regs = 4 consecutive t
        #pragma unroll
        for (int n = 0; n < 4; ++n) {
            const int c = ocol0 + n * 16 - 2048;
            const float bv = bias[ocol0 + n * 16];
            #pragma unroll
            for (int m = 0; m < 4; ++m) {
                const int row0 = orow0 + m * 16;
                const int bb = row0 >> 11, t0 = row0 & 2047;
                ushort4 pk;
                pk.x = f2b(acc[m][n][0] + bv);
                pk.y = f2b(acc[m][n][1] + bv);
                pk.z = f2b(acc[m][n][2] + bv);
                pk.w = f2b(acc[m][n][3] + bv);
                *(ushort4*)&vTout[((size_t)bb * Cn + c) * Tn + t0] = pk;
            }
        }
    } else {
        #pragma unroll
        for (int n = 0; n < 4; ++n) {
            const int col = ocol0 + n * 16;
            const float bv = bias[col];
            #pragma unroll
            for (int m = 0; m < 4; ++m) {
                #pragma unroll
                for (int r = 0; r < 4; ++r) {
                    const int row = orow0 + m * 16 + r;
                    const float v = acc[m][n][r] + bv;
                    if (OUT_BF16) outb[(size_t)row * N + col] = f2b(v);
                    else          outf[(size_t)row * N + col] = v;
                }
            }
        }
    }
}

// ---------------------------------------------------------------------------
// MFMA flash attention v4 (causal).
// Block = 4 waves; owns the PAIR {qtA=p, qtB=31-p}, processed in ONE kt-sweep:
// each K/V tile staged once; for kt<=qtA both tiles' dep-chains are live ->
// 32 MFMA + 2 independent softmaxes per barrier interval (ILP doubles).
// Flat grid 1024, XCD-grouped (8 heads/XCD -> K/V L2-resident).
// K/V staged via global_load_lds, double-buffered, both-sides XOR swizzle.
// Per-wave P LDS reused A->B (wave-in-order DS + compile fence).
// ---------------------------------------------------------------------------
__global__ __launch_bounds__(256) void attn_mfma4_kernel(
    const u16* __restrict__ qkvb, const u16* __restrict__ vT,
    u16* __restrict__ yb)
{
    __shared__ u16 Kb[2][64 * 64];   // [k-row][d-chunk swizzled]
    __shared__ u16 Vb[2][64 * 64];   // [d-row][k-chunk swizzled]
    __shared__ u16 Ps[4][16 * 64];   // per-wave P, same swizzle (shared A/B)

    const int tid = threadIdx.x;
    const int w   = tid >> 6;        // wave 0..3
    const int l   = tid & 63;
    const int l15 = l & 15;
    const int g   = l >> 4;          // lane group 0..3
    const int work = xcd_work(blockIdx.x, 1024);
    const int pr  = work & 15;       // pair index 0..15
    const int bh  = work >> 4;       // bh-major -> 8 bh per XCD
    const int b   = bh >> 4, h = bh & 15;

    const int qtA = pr, qtB = 31 - pr;
    const float S2 = 0.18033688f;    // 0.125 * log2(e)

    const u16* Kg = qkvb + (size_t)(b * Tn) * (3 * Cn) + Cn + h * HDn;
    const u16* Vg = vT + (size_t)bh * HDn * Tn;

    // staging decomposition
    const int srow = l >> 3;                   // 0..7
    const int schk = ((l & 7) ^ srow) << 3;    // swizzled source chunk (u16)
    const int rloc = w * 16;                   // wave's 16-row slice
    const int rsw  = (l15 & 7) << 3;           // read-side XOR key (u16)

    // Q B-frags for both tiles
    const u16* QpA = qkvb + (size_t)(b * Tn + qtA * 64 + w * 16 + l15) * (3 * Cn)
                     + h * HDn + (g << 3);
    const u16* QpB = qkvb + (size_t)(b * Tn + qtB * 64 + w * 16 + l15) * (3 * Cn)
                     + h * HDn + (g << 3);
    const bf16x8 qfA0 = *(const bf16x8*)(QpA);
    const bf16x8 qfA1 = *(const bf16x8*)(QpA + 32);
    const bf16x8 qfB0 = *(const bf16x8*)(QpB);
    const bf16x8 qfB1 = *(const bf16x8*)(QpB + 32);

    f32x4 OA[4], OB[4];
    float mA = -INFINITY, mB = -INFINITY, lsA = 0.f, lsB = 0.f;
    #pragma unroll
    for (int dc = 0; dc < 4; ++dc) {
        OA[dc] = (f32x4){0.f, 0.f, 0.f, 0.f};
        OB[dc] = (f32x4){0.f, 0.f, 0.f, 0.f};
    }

    // prologue: stage tile 0 -> buf 0
    #pragma unroll
    for (int jc = 0; jc < 2; ++jc) {
        const int rr = rloc + jc * 8;
        __builtin_amdgcn_global_load_lds(
            (const __attribute__((address_space(1))) u32*)
                (Kg + (size_t)(rr + srow) * (3 * Cn) + schk),
            (__attribute__((address_space(3))) u32*)&Kb[0][rr * 64], 16, 0, 0);
        __builtin_amdgcn_global_load_lds(
            (const __attribute__((address_space(1))) u32*)
                (Vg + (size_t)(rr + srow) * Tn + schk),
            (__attribute__((address_space(3))) u32*)&Vb[0][rr * 64], 16, 0, 0);
    }
    __syncthreads();

    int cur = 0;
    for (int kt = 0; kt <= qtB; ++kt) {
        if (kt < qtB) {
            #pragma unroll
            for (int jc = 0; jc < 2; ++jc) {
                const int rr = rloc + jc * 8;
                __builtin_amdgcn_global_load_lds(
                    (const __attribute__((address_space(1))) u32*)
                        (Kg + (size_t)((kt + 1) * 64 + rr + srow) * (3 * Cn) + schk),
                    (__attribute__((address_space(3))) u32*)
                        &Kb[cur ^ 1][rr * 64], 16, 0, 0);
                __builtin_amdgcn_global_load_lds(
                    (const __attribute__((address_space(1))) u32*)
                        (Vg + (size_t)(rr + srow) * Tn + (kt + 1) * 64 + schk),
                    (__attribute__((address_space(3))) u32*)
                        &Vb[cur ^ 1][rr * 64], 16, 0, 0);
            }
        }
        const u16* Kc = Kb[cur];
        const u16* Vc = Vb[cur];
        const bool actA = (kt <= qtA);

        // S^T = K Q^T for both tiles (independent MFMA chains)
        f32x4 SA[4], SB[4];
        __builtin_amdgcn_s_setprio(1);
        #pragma unroll
        for (int kc = 0; kc < 4; ++kc) {
            const bf16x8 k0 =
                *(const bf16x8*)&Kc[(kc * 16 + l15) * 64 + ((g << 3) ^ rsw)];
            const bf16x8 k1 =
                *(const bf16x8*)&Kc[(kc * 16 + l15) * 64 + ((32 + (g << 3)) ^ rsw)];
            f32x4 zb = (f32x4){0.f, 0.f, 0.f, 0.f};
            zb = __builtin_amdgcn_mfma_f32_16x16x32_bf16(k0, qfB0, zb, 0, 0, 0);
            SB[kc] = __builtin_amdgcn_mfma_f32_16x16x32_bf16(k1, qfB1, zb, 0, 0, 0);
            if (actA) {
                f32x4 za = (f32x4){0.f, 0.f, 0.f, 0.f};
                za = __builtin_amdgcn_mfma_f32_16x16x32_bf16(k0, qfA0, za, 0, 0, 0);
                SA[kc] = __builtin_amdgcn_mfma_f32_16x16x32_bf16(k1, qfA1, za, 0, 0, 0);
            }
        }
        __builtin_amdgcn_s_setprio(0);

        // causal masks (diagonal tiles only)
        if (kt == qtA && actA) {
            const int qg = qtA * 64 + w * 16 + l15;
            #pragma unroll
            for (int kc = 0; kc < 4; ++kc)
                #pragma unroll
                for (int r = 0; r < 4; ++r)
                    if (qtA * 64 + kc * 16 + g * 4 + r > qg) SA[kc][r] = -INFINITY;
        }
        if (kt == qtB) {
            const int qg = qtB * 64 + w * 16 + l15;
            #pragma unroll
            for (int kc = 0; kc < 4; ++kc)
                #pragma unroll
                for (int r = 0; r < 4; ++r)
                    if (qtB * 64 + kc * 16 + g * 4 + r > qg) SB[kc][r] = -INFINITY;
        }

        // ---- tile A: softmax + PV ----
        if (actA) {
            float m01 = fmaxf(fmaxf(SA[0][0], SA[0][1]), fmaxf(SA[0][2], SA[0][3]));
            float m23 = fmaxf(fmaxf(SA[1][0], SA[1][1]), fmaxf(SA[1][2], SA[1][3]));
            float m45 = fmaxf(fmaxf(SA[2][0], SA[2][1]), fmaxf(SA[2][2], SA[2][3]));
            float m67 = fmaxf(fmaxf(SA[3][0], SA[3][1]), fmaxf(SA[3][2], SA[3][3]));
            float mt = fmaxf(fmaxf(m01, m23), fmaxf(m45, m67));
            mt = fmaxf(mt, __shfl_xor(mt, 16));
            mt = fmaxf(mt, __shfl_xor(mt, 32));
            float lscale = 1.f;
            if (__any(!(mt <= mA + 64.f))) {
                const float mn = fmaxf(mA, mt);
                const float alpha = exp2f((mA - mn) * S2);
                mA = mn;
                float aO[4];
                #pragma unroll
                for (int r = 0; r < 4; ++r) aO[r] = __shfl(alpha, g * 4 + r);
                #pragma unroll
                for (int dc = 0; dc < 4; ++dc)
                    #pragma unroll
                    for (int r = 0; r < 4; ++r) OA[dc][r] *= aO[r];
                lscale = alpha;
            }
            float lt = 0.f;
            #pragma unroll
            for (int kc = 0; kc < 4; ++kc) {
                const float p0 = exp2f((SA[kc][0] - mA) * S2);
                const float p1 = exp2f((SA[kc][1] - mA) * S2);
                const float p2 = exp2f((SA[kc][2] - mA) * S2);
                const float p3 = exp2f((SA[kc][3] - mA) * S2);
                lt += (p0 + p1) + (p2 + p3);
                ushort4 pk;
                pk.x = f2b_fast(p0); pk.y = f2b_fast(p1);
                pk.z = f2b_fast(p2); pk.w = f2b_fast(p3);
                *(ushort4*)&Ps[w][(l15 << 6) + (((kc << 4) + (g << 2)) ^ rsw)] = pk;
            }
            lt += __shfl_xor(lt, 16);
            lt += __shfl_xor(lt, 32);
            lsA = lsA * lscale + lt;

            __builtin_amdgcn_s_setprio(1);
            #pragma unroll
            for (int hf = 0; hf < 2; ++hf) {
                const bf16x8 pf =
                    *(const bf16x8*)&Ps[w][(l15 << 6) + (((hf << 5) + (g << 3)) ^ rsw)];
                #pragma unroll
                for (int dc = 0; dc < 4; ++dc) {
                    const bf16x8 vf = *(const bf16x8*)
                        &Vc[(dc * 16 + l15) * 64 + ((((hf << 2) + g) << 3) ^ rsw)];
                    OA[dc] = __builtin_amdgcn_mfma_f32_16x16x32_bf16(pf, vf, OA[dc], 0, 0, 0);
                }
            }
            __builtin_amdgcn_s_setprio(0);
            asm volatile("" ::: "memory");  // keep PsA reads before PsB writes
        }

        // ---- tile B: softmax + PV ----
        {
            float m01 = fmaxf(fmaxf(SB[0][0], SB[0][1]), fmaxf(SB[0][2], SB[0][3]));
            float m23 = fmaxf(fmaxf(SB[1][0], SB[1][1]), fmaxf(SB[1][2], SB[1][3]));
            float m45 = fmaxf(fmaxf(SB[2][0], SB[2][1]), fmaxf(SB[2][2], SB[2][3]));
            float m67 = fmaxf(fmaxf(SB[3][0], SB[3][1]), fmaxf(SB[3][2], SB[3][3]));
            float mt = fmaxf(fmaxf(m01, m23), fmaxf(m45, m67));
            mt = fmaxf(mt, __shfl_xor(mt, 16));
            mt = fmaxf(mt, __shfl_xor(mt, 32));
            float lscale = 1.f;
            if (__any(!(mt <= mB + 64.f))) {
                const float mn = fmaxf(mB, mt);
                const float alpha = exp2f((mB - mn) * S2);
                mB = mn;
                float aO[4];
                #pragma unroll
                for (int r = 0; r < 4; ++r) aO[r] = __shfl(alpha, g * 4 + r);
                #pragma unroll
                for (int dc = 0; dc < 4; ++dc)
                    #pragma unroll
                    for (int r = 0; r < 4; ++r) OB[dc][r] *= aO[r];
                lscale = alpha;
            }
            float lt = 0.f;
            #pragma unroll
            for (int kc = 0; kc < 4; ++kc) {
                const float p0 = exp2f((SB[kc][0] - mB) * S2);
                const float p1 = exp2f((SB[kc][1] - mB) * S2);
                const float p2 = exp2f((SB[kc][2] - mB) * S2);
                const float p3 = exp2f((SB[kc][3] - mB) * S2);
                lt += (p0 + p1) + (p2 + p3);
                ushort4 pk;
                pk.x = f2b_fast(p0); pk.y = f2b_fast(p1);
                pk.z = f2b_fast(p2); pk.w = f2b_fast(p3);
                *(ushort4*)&Ps[w][(l15 << 6) + (((kc << 4) + (g << 2)) ^ rsw)] = pk;
            }
            lt += __shfl_xor(lt, 16);
            lt += __shfl_xor(lt, 32);
            lsB = lsB * lscale + lt;

            __builtin_amdgcn_s_setprio(1);
            #pragma unroll
            for (int hf = 0; hf < 2; ++hf) {
                const bf16x8 pf =
                    *(const bf16x8*)&Ps[w][(l15 << 6) + (((hf << 5) + (g << 3)) ^ rsw)];
                #pragma unroll
                for (int dc = 0; dc < 4; ++dc) {
                    const bf16x8 vf = *(const bf16x8*)
                        &Vc[(dc * 16 + l15) * 64 + ((((hf << 2) + g) << 3) ^ rsw)];
                    OB[dc] = __builtin_amdgcn_mfma_f32_16x16x32_bf16(pf, vf, OB[dc], 0, 0, 0);
                }
            }
            __builtin_amdgcn_s_setprio(0);
        }

        __syncthreads();  // drains DMA (vmcnt) + all waves done with buf
        cur ^= 1;
    }

    // epilogues: O rows are g*4+r; fetch their lsum via shuffle
    #pragma unroll
    for (int r = 0; r < 4; ++r) {
        const float lsa = __shfl(lsA, g * 4 + r);
        const float inva = 1.f / lsa;
        const size_t roA =
            (size_t)(b * Tn + qtA * 64 + w * 16 + g * 4 + r) * Cn + h * HDn;
        #pragma unroll
        for (int dc = 0; dc < 4; ++dc)
            yb[roA + dc * 16 + l15] = f2b(OA[dc][r] * inva);
        const float lsb = __shfl(lsB, g * 4 + r);
        const float invb = 1.f / lsb;
        const size_t roB =
            (size_t)(b * Tn + qtB * 64 + w * 16 + g * 4 + r) * Cn + h * HDn;
        #pragma unroll
        for (int dc = 0; dc < 4; ++dc)
            yb[roB + dc * 16 + l15] = f2b(OB[dc][r] * invb);
    }
}

// ---------------------------------------------------------------------------
extern "C" void kernel_launch(void* const* d_in, const int* in_sizes, int n_in,
                              void* d_out, int out_size, void* d_ws, size_t ws_size,
                              hipStream_t stream)
{
    const float* x      = (const float*)d_in[0];
    const float* W_attn = (const float*)d_in[1];
    const float* b_attn = (const float*)d_in[2];
    const float* W_proj = (const float*)d_in[3];
    const float* b_proj = (const float*)d_in[4];
    float* out = (float*)d_out;

    // Workspace (bf16): xb | WaT | WpT | qkvb | yb | vT  (~108 MB)
    u16* xb   = (u16*)d_ws;
    u16* WaT  = xb   + (size_t)Mn * Cn;
    u16* WpT  = WaT  + (size_t)3 * Cn * Cn;
    u16* qkvb = WpT  + (size_t)Cn * Cn;
    u16* yb   = qkvb + (size_t)Mn * 3 * Cn;
    u16* vT   = yb   + (size_t)Mn * Cn;

    cvt_f32_bf16_kernel<<<(Mn * Cn / 4 + 255) / 256, 256, 0, stream>>>(
        (const float4*)x, (ushort4*)xb, Mn * Cn / 4);

    transpose_cvt_kernel<<<dim3(3 * Cn / 32, Cn / 32), 256, 0, stream>>>(
        W_attn, WaT, Cn, 3 * Cn);
    transpose_cvt_kernel<<<dim3(Cn / 32, Cn / 32), 256, 0, stream>>>(
        W_proj, WpT, Cn, Cn);

    // qkv = x @ W_attn + b_attn; Q/K -> qkvb rows, V -> vT (fused transpose)
    gemm_bf16_kernel<true, true><<<24 * 64, 256, 0, stream>>>(
        xb, WaT, b_attn, qkvb, nullptr, vT, 3 * Cn, Cn, 24);

    // causal MFMA attention -> yb (bf16); flat grid 1024, XCD-grouped
    attn_mfma4_kernel<<<1024, 256, 0, stream>>>(qkvb, vT, yb);

    // out = y @ W_proj + b_proj (f32 out); flat grid 512 (8 x 64)
    gemm_bf16_kernel<false, false><<<8 * 64, 256, 0, stream>>>(
        yb, WpT, b_proj, nullptr, out, nullptr, Cn, Cn, 8);
}

// Round 7
// 214.727 us; speedup vs baseline: 1.1210x; 1.1210x over previous
//
#include <hip/hip_runtime.h>
#include <math.h>

// Problem constants
#define Bn 4
#define Tn 2048
#define Cn 1024
#define Hn 16
#define HDn 64
#define Mn (Bn * Tn)  // 8192 tokens

typedef unsigned short u16;
typedef unsigned int u32;
typedef __attribute__((ext_vector_type(8))) short bf16x8;        // 8 bf16 = 4 VGPRs
typedef __attribute__((ext_vector_type(8))) unsigned short us8;  // 16B chunk
typedef __attribute__((ext_vector_type(4))) float f32x4;         // MFMA accumulator

__device__ __forceinline__ float b2f(u16 u) {
    return __uint_as_float(((u32)u) << 16);
}
__device__ __forceinline__ u16 f2b(float f) {
    u32 u = __float_as_uint(f);
    return (u16)((u + 0x7FFFu + ((u >> 16) & 1u)) >> 16);  // RNE
}

// XCD-grouped work id from flat block id (requires gridDim.x % 8 == 0).
__device__ __forceinline__ int xcd_work(int bid, int nwg) {
    return (bid & 7) * (nwg >> 3) + (bid >> 3);
}

// global_load_lds, width 16 (literal size required)
#define GLL(srcp, dstp)                                                     \
    __builtin_amdgcn_global_load_lds(                                       \
        (const __attribute__((address_space(1))) u32*)(srcp),               \
        (__attribute__((address_space(3))) u32*)(dstp), 16, 0, 0)

// ---------------------------------------------------------------------------
// fp32 -> bf16 elementwise convert
// ---------------------------------------------------------------------------
__global__ __launch_bounds__(256) void cvt_f32_bf16_kernel(
    const float4* __restrict__ in, ushort4* __restrict__ out, int n4)
{
    int i = blockIdx.x * 256 + threadIdx.x;
    if (i < n4) {
        float4 v = in[i];
        ushort4 o;
        o.x = f2b(v.x); o.y = f2b(v.y); o.z = f2b(v.z); o.w = f2b(v.w);
        out[i] = o;
    }
}

// ---------------------------------------------------------------------------
// Transpose + convert: in [R,Cc] fp32 -> out [Cc,R] bf16. 32x32 LDS tiles.
// ---------------------------------------------------------------------------
__global__ __launch_bounds__(256) void transpose_cvt_kernel(
    const float* __restrict__ in, u16* __restrict__ out, int R, int Cc)
{
    __shared__ u16 t[32][33];
    const int c0 = blockIdx.x * 32, r0 = blockIdx.y * 32;
    const int tx = threadIdx.x & 31, ty = threadIdx.x >> 5;  // 32 x 8
    #pragma unroll
    for (int i = 0; i < 32; i += 8)
        t[ty + i][tx] = f2b(in[(size_t)(r0 + ty + i) * Cc + c0 + tx]);
    __syncthreads();
    #pragma unroll
    for (int i = 0; i < 32; i += 8)
        out[(size_t)(c0 + ty + i) * R + r0 + tx] = t[tx][ty + i];
}

// ---------------------------------------------------------------------------
// bf16 MFMA GEMM (m97 structure): Out[M,N] = A[M,K] @ BT[N,K]^T + bias[N]
// 128x128 tile, BK=32, 4 waves, global_load_lds width=16 staging, flat grid
// with XCD-grouped work remap.
// QKV_MODE: output cols >= 2048 (the V section) are written TRANSPOSED into
// vT[b][c][t]; 4 acc regs = 4 consecutive t -> one ushort4 store.
// ---------------------------------------------------------------------------
template <bool OUT_BF16, bool QKV_MODE>
__global__ __launch_bounds__(256) void gemm_bf16_kernel(
    const u16* __restrict__ A, const u16* __restrict__ BT,
    const float* __restrict__ bias,
    u16* __restrict__ outb, float* __restrict__ outf, u16* __restrict__ vTout,
    int N, int K, int nx)
{
    __shared__ u16 Al[128 * 32];
    __shared__ u16 Bl[128 * 32];

    const int tid = threadIdx.x;
    const int workid = xcd_work(blockIdx.x, gridDim.x);
    const int brow = (workid / nx) * 128;
    const int bcol = (workid % nx) * 128;
    const int w  = tid >> 6;
    const int wr = w >> 1, wc = w & 1;
    const int l  = tid & 63;
    const int lr = l & 15;
    const int lk = (l >> 4) << 3;

    f32x4 acc[4][4];
    #pragma unroll
    for (int m = 0; m < 4; ++m)
        #pragma unroll
        for (int n = 0; n < 4; ++n) acc[m][n] = (f32x4){0.f, 0.f, 0.f, 0.f};

    for (int k0 = 0; k0 < K; k0 += 32) {
        __syncthreads();  // protect prior iteration's fragment reads
        #pragma unroll
        for (int i = 0; i < 2; ++i) {
            const int c   = i * 256 + tid;    // chunk 0..511
            const int row = c >> 2;           // 0..127
            const int col = (c & 3) << 3;     // 0,8,16,24
            GLL(&A [(size_t)(brow + row) * K + k0 + col],
                &Al[(size_t)(i * 256 + (tid & 192)) * 8]);
            GLL(&BT[(size_t)(bcol + row) * K + k0 + col],
                &Bl[(size_t)(i * 256 + (tid & 192)) * 8]);
        }
        __syncthreads();

        bf16x8 a[4], b[4];
        #pragma unroll
        for (int m = 0; m < 4; ++m)
            a[m] = *(const bf16x8*)&Al[(wr * 64 + m * 16 + lr) * 32 + lk];
        #pragma unroll
        for (int n = 0; n < 4; ++n)
            b[n] = *(const bf16x8*)&Bl[(wc * 64 + n * 16 + lr) * 32 + lk];

        __builtin_amdgcn_s_setprio(1);
        #pragma unroll
        for (int m = 0; m < 4; ++m)
            #pragma unroll
            for (int n = 0; n < 4; ++n)
                acc[m][n] = __builtin_amdgcn_mfma_f32_16x16x32_bf16(
                    a[m], b[n], acc[m][n], 0, 0, 0);
        __builtin_amdgcn_s_setprio(0);
    }

    // Epilogue. C/D layout: col = lane&15, row = (lane>>4)*4 + reg.
    const int orow0 = brow + wr * 64 + ((l >> 4) << 2);
    const int ocol0 = bcol + wc * 64 + lr;
    if (QKV_MODE && bcol >= 2048) {
        #pragma unroll
        for (int n = 0; n < 4; ++n) {
            const int c = ocol0 + n * 16 - 2048;
            const float bv = bias[ocol0 + n * 16];
            #pragma unroll
            for (int m = 0; m < 4; ++m) {
                const int row0 = orow0 + m * 16;
                const int bb = row0 >> 11, t0 = row0 & 2047;
                ushort4 pk;
                pk.x = f2b(acc[m][n][0] + bv);
                pk.y = f2b(acc[m][n][1] + bv);
                pk.z = f2b(acc[m][n][2] + bv);
                pk.w = f2b(acc[m][n][3] + bv);
                *(ushort4*)&vTout[((size_t)bb * Cn + c) * Tn + t0] = pk;
            }
        }
    } else {
        #pragma unroll
        for (int n = 0; n < 4; ++n) {
            const int col = ocol0 + n * 16;
            const float bv = bias[col];
            #pragma unroll
            for (int m = 0; m < 4; ++m) {
                #pragma unroll
                for (int r = 0; r < 4; ++r) {
                    const int row = orow0 + m * 16 + r;
                    const float v = acc[m][n][r] + bv;
                    if (OUT_BF16) outb[(size_t)row * N + col] = f2b(v);
                    else          outf[(size_t)row * N + col] = v;
                }
            }
        }
    }
}

// ---------------------------------------------------------------------------
// Per-group online-softmax step: S[4] (16 k-values for q-row l15 of this
// group), updates m/ls/O, writes bf16 P row via v_cvt_pk_bf16_f32.
// Prow = per-lane pointer to this lane's P row (already includes group+l15).
// ---------------------------------------------------------------------------
__device__ __forceinline__ void softmax_step(
    f32x4 S[4], float& m, float& ls, f32x4 O[4],
    u16* __restrict__ Prow, int g, int rsw, float S2)
{
    float ma = fmaxf(fmaxf(S[0][0], S[0][1]), fmaxf(S[0][2], S[0][3]));
    float mb = fmaxf(fmaxf(S[1][0], S[1][1]), fmaxf(S[1][2], S[1][3]));
    float mc = fmaxf(fmaxf(S[2][0], S[2][1]), fmaxf(S[2][2], S[2][3]));
    float md = fmaxf(fmaxf(S[3][0], S[3][1]), fmaxf(S[3][2], S[3][3]));
    float mt = fmaxf(fmaxf(ma, mb), fmaxf(mc, md));
    mt = fmaxf(mt, __shfl_xor(mt, 16));
    mt = fmaxf(mt, __shfl_xor(mt, 32));

    float lscale = 1.f;
    if (__any(!(mt <= m + 64.f))) {   // defer-max: 64 raw = 8 post-scale
        const float mn = fmaxf(m, mt);
        const float alpha = exp2f((m - mn) * S2);
        m = mn;
        float aO[4];
        #pragma unroll
        for (int r = 0; r < 4; ++r) aO[r] = __shfl(alpha, g * 4 + r);
        #pragma unroll
        for (int dc = 0; dc < 4; ++dc)
            #pragma unroll
            for (int r = 0; r < 4; ++r) O[dc][r] *= aO[r];
        lscale = alpha;
    }

    float lt = 0.f;
    #pragma unroll
    for (int kc = 0; kc < 4; ++kc) {
        const float p0 = exp2f((S[kc][0] - m) * S2);
        const float p1 = exp2f((S[kc][1] - m) * S2);
        const float p2 = exp2f((S[kc][2] - m) * S2);
        const float p3 = exp2f((S[kc][3] - m) * S2);
        lt += (p0 + p1) + (p2 + p3);
        u32 lo, hi;
        asm("v_cvt_pk_bf16_f32 %0, %1, %2" : "=v"(lo) : "v"(p0), "v"(p1));
        asm("v_cvt_pk_bf16_f32 %0, %1, %2" : "=v"(hi) : "v"(p2), "v"(p3));
        uint2 pk; pk.x = lo; pk.y = hi;
        *(uint2*)&Prow[((kc << 4) + (g << 2)) ^ rsw] = pk;
    }
    lt += __shfl_xor(lt, 16);
    lt += __shfl_xor(lt, 32);
    ls = ls * lscale + lt;
}

// ---------------------------------------------------------------------------
// MFMA flash attention v5 (causal).
// Block = 4 waves; wave owns 32 q-rows (two 16-row groups SHARING every K/V
// fragment read -> LDS read traffic per q-row halved vs v3). Q-tile = 128
// rows; pairs {p, 15-p} -> 34 uniform kt-steps; grid 512 = 2 blocks/CU.
// K/V via global_load_lds, double-buffered, both-sides XOR swizzle (v3-
// verified). Swapped QK^T; defer-max; cvt_pk P-pack; setprio on MFMA.
// ---------------------------------------------------------------------------
__global__ __launch_bounds__(256, 2) void attn_mfma5_kernel(
    const u16* __restrict__ qkvb, const u16* __restrict__ vT,
    u16* __restrict__ yb)
{
    __shared__ u16 Kb[2][64 * 64];   // [k-row][d-chunk swizzled]
    __shared__ u16 Vb[2][64 * 64];   // [d-row][k-chunk swizzled]
    __shared__ u16 Ps[4][32 * 64];   // per-wave P (rows 0-15 grp0, 16-31 grp1)

    const int tid = threadIdx.x;
    const int w   = tid >> 6;        // wave 0..3
    const int l   = tid & 63;
    const int l15 = l & 15;
    const int g   = l >> 4;          // lane group 0..3
    const int work = xcd_work(blockIdx.x, 512);
    const int pr  = work & 7;        // pair index 0..7
    const int bh  = work >> 3;       // 8 bh per XCD -> K/V L2-resident
    const int b   = bh >> 4, h = bh & 15;

    const float S2 = 0.18033688f;    // 0.125 * log2(e)

    const u16* Kg = qkvb + (size_t)(b * Tn) * (3 * Cn) + Cn + h * HDn;
    const u16* Vg = vT + (size_t)bh * HDn * Tn;

    const int srow = l >> 3;                   // 0..7
    const int schk = ((l & 7) ^ srow) << 3;    // swizzled source chunk (u16)
    const int rloc = w * 16;                   // wave's staging row slice
    const int rsw  = (l15 & 7) << 3;           // read-side XOR key (u16)

    u16* const Prow0 = &Ps[w][(size_t)l15 << 6];
    u16* const Prow1 = Prow0 + (16 << 6);

    #pragma unroll 1
    for (int half = 0; half < 2; ++half) {
        const int qt = half ? (15 - pr) : pr;   // 128-row tile index
        const int ktmax = 2 * qt + 2;
        const int qrow0 = qt * 128 + w * 32;    // wave's first q row

        // Q B-frags for both 16-row groups (2 d-halves each)
        const u16* Qp0 = qkvb + (size_t)(b * Tn + qrow0 + l15) * (3 * Cn)
                         + h * HDn + (g << 3);
        const u16* Qp1 = Qp0 + (size_t)16 * (3 * Cn);
        const bf16x8 qf00 = *(const bf16x8*)(Qp0);
        const bf16x8 qf01 = *(const bf16x8*)(Qp0 + 32);
        const bf16x8 qf10 = *(const bf16x8*)(Qp1);
        const bf16x8 qf11 = *(const bf16x8*)(Qp1 + 32);

        f32x4 O0[4], O1[4];
        float m0 = -INFINITY, m1 = -INFINITY, ls0 = 0.f, ls1 = 0.f;
        #pragma unroll
        for (int dc = 0; dc < 4; ++dc) {
            O0[dc] = (f32x4){0.f, 0.f, 0.f, 0.f};
            O1[dc] = (f32x4){0.f, 0.f, 0.f, 0.f};
        }

        // prologue: stage kt=0 into buf 0
        #pragma unroll
        for (int jc = 0; jc < 2; ++jc) {
            const int rr = rloc + jc * 8;
            GLL(Kg + (size_t)(rr + srow) * (3 * Cn) + schk, &Kb[0][rr * 64]);
            GLL(Vg + (size_t)(rr + srow) * Tn + schk,       &Vb[0][rr * 64]);
        }
        __syncthreads();

        int cur = 0;
        for (int kt = 0; kt < ktmax; ++kt) {
            if (kt + 1 < ktmax) {   // prefetch next tile into buf^1
                #pragma unroll
                for (int jc = 0; jc < 2; ++jc) {
                    const int rr = rloc + jc * 8;
                    GLL(Kg + (size_t)((kt + 1) * 64 + rr + srow) * (3 * Cn) + schk,
                        &Kb[cur ^ 1][rr * 64]);
                    GLL(Vg + (size_t)(rr + srow) * Tn + (kt + 1) * 64 + schk,
                        &Vb[cur ^ 1][rr * 64]);
                }
            }
            const u16* Kc = Kb[cur];
            const u16* Vc = Vb[cur];

            if (kt * 64 <= qrow0 + 31) {   // wave has unmasked work
                // S^T = K Q^T for both groups; K-frags read ONCE
                f32x4 S0[4], S1[4];
                __builtin_amdgcn_s_setprio(1);
                #pragma unroll
                for (int kc = 0; kc < 4; ++kc) {
                    const bf16x8 k0 =
                        *(const bf16x8*)&Kc[(kc * 16 + l15) * 64 + ((g << 3) ^ rsw)];
                    const bf16x8 k1 =
                        *(const bf16x8*)&Kc[(kc * 16 + l15) * 64 + ((32 + (g << 3)) ^ rsw)];
                    f32x4 z0 = (f32x4){0.f, 0.f, 0.f, 0.f};
                    z0 = __builtin_amdgcn_mfma_f32_16x16x32_bf16(k0, qf00, z0, 0, 0, 0);
                    S0[kc] = __builtin_amdgcn_mfma_f32_16x16x32_bf16(k1, qf01, z0, 0, 0, 0);
                    f32x4 z1 = (f32x4){0.f, 0.f, 0.f, 0.f};
                    z1 = __builtin_amdgcn_mfma_f32_16x16x32_bf16(k0, qf10, z1, 0, 0, 0);
                    S1[kc] = __builtin_amdgcn_mfma_f32_16x16x32_bf16(k1, qf11, z1, 0, 0, 0);
                }
                __builtin_amdgcn_s_setprio(0);

                // causal masks (only when tile straddles the diagonal)
                if (kt * 64 + 63 > qrow0) {
                    const int qg = qrow0 + l15;
                    #pragma unroll
                    for (int kc = 0; kc < 4; ++kc)
                        #pragma unroll
                        for (int r = 0; r < 4; ++r)
                            if (kt * 64 + kc * 16 + g * 4 + r > qg)
                                S0[kc][r] = -INFINITY;
                }
                if (kt * 64 + 63 > qrow0 + 16) {
                    const int qg = qrow0 + 16 + l15;
                    #pragma unroll
                    for (int kc = 0; kc < 4; ++kc)
                        #pragma unroll
                        for (int r = 0; r < 4; ++r)
                            if (kt * 64 + kc * 16 + g * 4 + r > qg)
                                S1[kc][r] = -INFINITY;
                }

                softmax_step(S0, m0, ls0, O0, Prow0, g, rsw, S2);
                softmax_step(S1, m1, ls1, O1, Prow1, g, rsw, S2);

                // O += P @ V ; V-frags read ONCE for both groups
                __builtin_amdgcn_s_setprio(1);
                #pragma unroll
                for (int hf = 0; hf < 2; ++hf) {
                    const bf16x8 pf0 =
                        *(const bf16x8*)&Prow0[((hf << 5) + (g << 3)) ^ rsw];
                    const bf16x8 pf1 =
                        *(const bf16x8*)&Prow1[((hf << 5) + (g << 3)) ^ rsw];
                    #pragma unroll
                    for (int dc = 0; dc < 4; ++dc) {
                        const bf16x8 vf = *(const bf16x8*)
                            &Vc[(dc * 16 + l15) * 64 + ((((hf << 2) + g) << 3) ^ rsw)];
                        O0[dc] = __builtin_amdgcn_mfma_f32_16x16x32_bf16(pf0, vf, O0[dc], 0, 0, 0);
                        O1[dc] = __builtin_amdgcn_mfma_f32_16x16x32_bf16(pf1, vf, O1[dc], 0, 0, 0);
                    }
                }
                __builtin_amdgcn_s_setprio(0);
            }

            __syncthreads();  // drains DMA (vmcnt) + all waves done with buf
            cur ^= 1;
        }

        // epilogue: O rows are g*4+r; lsum/m uniform across g after shuffles
        #pragma unroll
        for (int r = 0; r < 4; ++r) {
            const float inv0 = __builtin_amdgcn_rcpf(__shfl(ls0, g * 4 + r));
            const size_t ro0 =
                (size_t)(b * Tn + qrow0 + g * 4 + r) * Cn + h * HDn;
            #pragma unroll
            for (int dc = 0; dc < 4; ++dc)
                yb[ro0 + dc * 16 + l15] = f2b(O0[dc][r] * inv0);
            const float inv1 = __builtin_amdgcn_rcpf(__shfl(ls1, g * 4 + r));
            const size_t ro1 =
                (size_t)(b * Tn + qrow0 + 16 + g * 4 + r) * Cn + h * HDn;
            #pragma unroll
            for (int dc = 0; dc < 4; ++dc)
                yb[ro1 + dc * 16 + l15] = f2b(O1[dc][r] * inv1);
        }
    }
}

// ---------------------------------------------------------------------------
extern "C" void kernel_launch(void* const* d_in, const int* in_sizes, int n_in,
                              void* d_out, int out_size, void* d_ws, size_t ws_size,
                              hipStream_t stream)
{
    const float* x      = (const float*)d_in[0];
    const float* W_attn = (const float*)d_in[1];
    const float* b_attn = (const float*)d_in[2];
    const float* W_proj = (const float*)d_in[3];
    const float* b_proj = (const float*)d_in[4];
    float* out = (float*)d_out;

    // Workspace (bf16): xb | WaT | WpT | qkvb | yb | vT  (~108 MB)
    u16* xb   = (u16*)d_ws;
    u16* WaT  = xb   + (size_t)Mn * Cn;
    u16* WpT  = WaT  + (size_t)3 * Cn * Cn;
    u16* qkvb = WpT  + (size_t)Cn * Cn;
    u16* yb   = qkvb + (size_t)Mn * 3 * Cn;
    u16* vT   = yb   + (size_t)Mn * Cn;

    cvt_f32_bf16_kernel<<<(Mn * Cn / 4 + 255) / 256, 256, 0, stream>>>(
        (const float4*)x, (ushort4*)xb, Mn * Cn / 4);

    transpose_cvt_kernel<<<dim3(3 * Cn / 32, Cn / 32), 256, 0, stream>>>(
        W_attn, WaT, Cn, 3 * Cn);
    transpose_cvt_kernel<<<dim3(Cn / 32, Cn / 32), 256, 0, stream>>>(
        W_proj, WpT, Cn, Cn);

    // qkv = x @ W_attn + b_attn; Q/K -> qkvb rows, V -> vT (fused transpose)
    gemm_bf16_kernel<true, true><<<24 * 64, 256, 0, stream>>>(
        xb, WaT, b_attn, qkvb, nullptr, vT, 3 * Cn, Cn, 24);

    // causal MFMA attention -> yb (bf16); grid 512, XCD-grouped
    attn_mfma5_kernel<<<512, 256, 0, stream>>>(qkvb, vT, yb);

    // out = y @ W_proj + b_proj (f32 out)
    gemm_bf16_kernel<false, false><<<8 * 64, 256, 0, stream>>>(
        yb, WpT, b_proj, nullptr, out, nullptr, Cn, Cn, 8);
}

// Round 8
// 202.426 us; speedup vs baseline: 1.1891x; 1.0608x over previous
//
#include <hip/hip_runtime.h>
#include <math.h>

// Problem constants
#define Bn 4
#define Tn 2048
#define Cn 1024
#define Hn 16
#define HDn 64
#define Mn (Bn * Tn)  // 8192 tokens

typedef unsigned short u16;
typedef unsigned int u32;
typedef __attribute__((ext_vector_type(8))) short bf16x8;        // 8 bf16 = 4 VGPRs
typedef __attribute__((ext_vector_type(8))) unsigned short us8;  // 16B chunk
typedef __attribute__((ext_vector_type(4))) float f32x4;         // 16x16 MFMA acc
typedef __attribute__((ext_vector_type(16))) float f32x16;       // 32x32 MFMA acc
typedef __attribute__((ext_vector_type(4))) unsigned int u32x4;

__device__ __forceinline__ float b2f(u16 u) {
    return __uint_as_float(((u32)u) << 16);
}
__device__ __forceinline__ u16 f2b(float f) {
    u32 u = __float_as_uint(f);
    return (u16)((u + 0x7FFFu + ((u >> 16) & 1u)) >> 16);  // RNE
}
__device__ __forceinline__ u32 cvtpk(float a, float b) {   // {lo:bf16(a), hi:bf16(b)}
    u32 d;
    asm("v_cvt_pk_bf16_f32 %0, %1, %2" : "=v"(d) : "v"(a), "v"(b));
    return d;
}
// v_permlane32_swap_b32: a[32..63] <-> b[0..31]
__device__ __forceinline__ void pswap(u32& a, u32& b) {
    asm("v_permlane32_swap_b32 %0, %1" : "+v"(a), "+v"(b));
}

// XCD-grouped work id from flat block id (requires gridDim.x % 8 == 0).
__device__ __forceinline__ int xcd_work(int bid, int nwg) {
    return (bid & 7) * (nwg >> 3) + (bid >> 3);
}

// global_load_lds, width 16 (literal size required)
#define GLL(srcp, dstp)                                                     \
    __builtin_amdgcn_global_load_lds(                                       \
        (const __attribute__((address_space(1))) u32*)(srcp),               \
        (__attribute__((address_space(3))) u32*)(dstp), 16, 0, 0)

// ---------------------------------------------------------------------------
// fp32 -> bf16 elementwise convert
// ---------------------------------------------------------------------------
__global__ __launch_bounds__(256) void cvt_f32_bf16_kernel(
    const float4* __restrict__ in, ushort4* __restrict__ out, int n4)
{
    int i = blockIdx.x * 256 + threadIdx.x;
    if (i < n4) {
        float4 v = in[i];
        ushort4 o;
        o.x = f2b(v.x); o.y = f2b(v.y); o.z = f2b(v.z); o.w = f2b(v.w);
        out[i] = o;
    }
}

// ---------------------------------------------------------------------------
// Transpose + convert: in [R,Cc] fp32 -> out [Cc,R] bf16. 32x32 LDS tiles.
// ---------------------------------------------------------------------------
__global__ __launch_bounds__(256) void transpose_cvt_kernel(
    const float* __restrict__ in, u16* __restrict__ out, int R, int Cc)
{
    __shared__ u16 t[32][33];
    const int c0 = blockIdx.x * 32, r0 = blockIdx.y * 32;
    const int tx = threadIdx.x & 31, ty = threadIdx.x >> 5;  // 32 x 8
    #pragma unroll
    for (int i = 0; i < 32; i += 8)
        t[ty + i][tx] = f2b(in[(size_t)(r0 + ty + i) * Cc + c0 + tx]);
    __syncthreads();
    #pragma unroll
    for (int i = 0; i < 32; i += 8)
        out[(size_t)(c0 + ty + i) * R + r0 + tx] = t[tx][ty + i];
}

// ---------------------------------------------------------------------------
// bf16 MFMA GEMM (m97 structure): Out[M,N] = A[M,K] @ BT[N,K]^T + bias[N]
// 128x128 tile, BK=32, 4 waves, global_load_lds width=16 staging, flat grid
// with XCD-grouped work remap.
// QKV_MODE: output cols >= 2048 (the V section) are written TRANSPOSED into
// vT[b][c][t]; 4 acc regs = 4 consecutive t -> one ushort4 store.
// ---------------------------------------------------------------------------
template <bool OUT_BF16, bool QKV_MODE>
__global__ __launch_bounds__(256) void gemm_bf16_kernel(
    const u16* __restrict__ A, const u16* __restrict__ BT,
    const float* __restrict__ bias,
    u16* __restrict__ outb, float* __restrict__ outf, u16* __restrict__ vTout,
    int N, int K, int nx)
{
    __shared__ u16 Al[128 * 32];
    __shared__ u16 Bl[128 * 32];

    const int tid = threadIdx.x;
    const int workid = xcd_work(blockIdx.x, gridDim.x);
    const int brow = (workid / nx) * 128;
    const int bcol = (workid % nx) * 128;
    const int w  = tid >> 6;
    const int wr = w >> 1, wc = w & 1;
    const int l  = tid & 63;
    const int lr = l & 15;
    const int lk = (l >> 4) << 3;

    f32x4 acc[4][4];
    #pragma unroll
    for (int m = 0; m < 4; ++m)
        #pragma unroll
        for (int n = 0; n < 4; ++n) acc[m][n] = (f32x4){0.f, 0.f, 0.f, 0.f};

    for (int k0 = 0; k0 < K; k0 += 32) {
        __syncthreads();  // protect prior iteration's fragment reads
        #pragma unroll
        for (int i = 0; i < 2; ++i) {
            const int c   = i * 256 + tid;    // chunk 0..511
            const int row = c >> 2;           // 0..127
            const int col = (c & 3) << 3;     // 0,8,16,24
            GLL(&A [(size_t)(brow + row) * K + k0 + col],
                &Al[(size_t)(i * 256 + (tid & 192)) * 8]);
            GLL(&BT[(size_t)(bcol + row) * K + k0 + col],
                &Bl[(size_t)(i * 256 + (tid & 192)) * 8]);
        }
        __syncthreads();

        bf16x8 a[4], b[4];
        #pragma unroll
        for (int m = 0; m < 4; ++m)
            a[m] = *(const bf16x8*)&Al[(wr * 64 + m * 16 + lr) * 32 + lk];
        #pragma unroll
        for (int n = 0; n < 4; ++n)
            b[n] = *(const bf16x8*)&Bl[(wc * 64 + n * 16 + lr) * 32 + lk];

        __builtin_amdgcn_s_setprio(1);
        #pragma unroll
        for (int m = 0; m < 4; ++m)
            #pragma unroll
            for (int n = 0; n < 4; ++n)
                acc[m][n] = __builtin_amdgcn_mfma_f32_16x16x32_bf16(
                    a[m], b[n], acc[m][n], 0, 0, 0);
        __builtin_amdgcn_s_setprio(0);
    }

    // Epilogue. C/D layout: col = lane&15, row = (lane>>4)*4 + reg.
    const int orow0 = brow + wr * 64 + ((l >> 4) << 2);
    const int ocol0 = bcol + wc * 64 + lr;
    if (QKV_MODE && bcol >= 2048) {
        #pragma unroll
        for (int n = 0; n < 4; ++n) {
            const int c = ocol0 + n * 16 - 2048;
            const float bv = bias[ocol0 + n * 16];
            #pragma unroll
            for (int m = 0; m < 4; ++m) {
                const int row0 = orow0 + m * 16;
                const int bb = row0 >> 11, t0 = row0 & 2047;
                ushort4 pk;
                pk.x = f2b(acc[m][n][0] + bv);
                pk.y = f2b(acc[m][n][1] + bv);
                pk.z = f2b(acc[m][n][2] + bv);
                pk.w = f2b(acc[m][n][3] + bv);
                *(ushort4*)&vTout[((size_t)bb * Cn + c) * Tn + t0] = pk;
            }
        }
    } else {
        #pragma unroll
        for (int n = 0; n < 4; ++n) {
            const int col = ocol0 + n * 16;
            const float bv = bias[col];
            #pragma unroll
            for (int m = 0; m < 4; ++m) {
                #pragma unroll
                for (int r = 0; r < 4; ++r) {
                    const int row = orow0 + m * 16 + r;
                    const float v = acc[m][n][r] + bv;
                    if (OUT_BF16) outb[(size_t)row * N + col] = f2b(v);
                    else          outf[(size_t)row * N + col] = v;
                }
            }
        }
    }
}

// ---------------------------------------------------------------------------
// MFMA flash attention v6 (causal) - 32x32 MFMA, in-register softmax (T12).
// Block = 4 waves; wave owns 32 q-rows. Q-tile = 128 rows; pairs {p, 15-p} ->
// 34 uniform kt-steps; grid 512, XCD-grouped (8 heads/XCD -> K/V L2-fit).
// Swapped QK^T: S^T = mfma32(A=K, B=Q) -> col=lane&31 = q-row: the entire
// 64-k P-row is lane-local (split lane/lane+32) -> row-reduce = 31 in-lane
// ops + ONE shfl_xor(32). P -> A-frags via 16 cvt_pk + 8 permlane32_swap in
// registers (no P-LDS). PV: mfma32(A=P, B=V) with V read as contiguous
// swizzled b128 from the [d][k] vT-staged tile. K/V via global_load_lds,
// double-buffered, both-sides XOR swizzle (v3/v5-verified geometry).
// ---------------------------------------------------------------------------
__global__ __launch_bounds__(256, 2) void attn_mfma6_kernel(
    const u16* __restrict__ qkvb, const u16* __restrict__ vT,
    u16* __restrict__ yb)
{
    __shared__ u16 Kb[2][64 * 64];   // [k-row][d-chunk swizzled]
    __shared__ u16 Vb[2][64 * 64];   // [d-row][k-chunk swizzled]

    const int tid = threadIdx.x;
    const int w   = tid >> 6;        // wave 0..3
    const int l   = tid & 63;
    const int q31 = l & 31;          // q (QK^T B-col) / d (PV B-col)
    const int hi  = l >> 5;
    const int work = xcd_work(blockIdx.x, 512);
    const int pr  = work & 7;        // pair index 0..7
    const int bh  = work >> 3;       // 8 bh per XCD
    const int b   = bh >> 4, h = bh & 15;

    const float S2 = 0.18033688f;    // 0.125 * log2(e)

    const u16* Kg = qkvb + (size_t)(b * Tn) * (3 * Cn) + Cn + h * HDn;
    const u16* Vg = vT + (size_t)bh * HDn * Tn;

    const int srow = l >> 3;                   // staging row 0..7
    const int schk = ((l & 7) ^ srow) << 3;    // swizzled source chunk (u16)
    const int rloc = w * 16;                   // wave's staging row slice
    const int rsw8 = q31 & 7;                  // read-side XOR key (chunk idx)

    #pragma unroll 1
    for (int half = 0; half < 2; ++half) {
        const int qt = half ? (15 - pr) : pr;   // 128-row tile index
        const int ktmax = 2 * qt + 2;
        const int qrow0 = qt * 128 + w * 32;    // wave's first q row
        const int qglob = qrow0 + q31;          // this lane's q row

        // Q B-frags: qf[c] = Q[qglob][c*16 + hi*8 .. +7]
        const u16* Qp = qkvb + (size_t)(b * Tn + qglob) * (3 * Cn)
                        + h * HDn + hi * 8;
        bf16x8 qf[4];
        #pragma unroll
        for (int c = 0; c < 4; ++c) qf[c] = *(const bf16x8*)(Qp + c * 16);

        f32x16 O0, O1;
        #pragma unroll
        for (int r = 0; r < 16; ++r) { O0[r] = 0.f; O1[r] = 0.f; }
        float m = -INFINITY, ls = 0.f;

        // prologue: stage kt=0 into buf 0
        #pragma unroll
        for (int jc = 0; jc < 2; ++jc) {
            const int rr = rloc + jc * 8;
            GLL(Kg + (size_t)(rr + srow) * (3 * Cn) + schk, &Kb[0][rr * 64]);
            GLL(Vg + (size_t)(rr + srow) * Tn + schk,       &Vb[0][rr * 64]);
        }
        __syncthreads();

        int cur = 0;
        for (int kt = 0; kt < ktmax; ++kt) {
            if (kt + 1 < ktmax) {   // prefetch next tile into buf^1
                #pragma unroll
                for (int jc = 0; jc < 2; ++jc) {
                    const int rr = rloc + jc * 8;
                    GLL(Kg + (size_t)((kt + 1) * 64 + rr + srow) * (3 * Cn) + schk,
                        &Kb[cur ^ 1][rr * 64]);
                    GLL(Vg + (size_t)(rr + srow) * Tn + (kt + 1) * 64 + schk,
                        &Vb[cur ^ 1][rr * 64]);
                }
            }
            const u16* Kc = Kb[cur];
            const u16* Vc = Vb[cur];

            if (kt * 64 <= qrow0 + 31) {   // wave has unmasked work
                // S^T = K Q^T : two 32x32 tiles (k 0..31, 32..63)
                f32x16 S0, S1;
                #pragma unroll
                for (int r = 0; r < 16; ++r) { S0[r] = 0.f; S1[r] = 0.f; }
                __builtin_amdgcn_s_setprio(1);
                #pragma unroll
                for (int c = 0; c < 4; ++c) {
                    const int co = ((2 * c + hi) ^ rsw8) << 3;
                    const bf16x8 k0 = *(const bf16x8*)&Kc[q31 * 64 + co];
                    const bf16x8 k1 = *(const bf16x8*)&Kc[(32 + q31) * 64 + co];
                    S0 = __builtin_amdgcn_mfma_f32_32x32x16_bf16(k0, qf[c], S0, 0, 0, 0);
                    S1 = __builtin_amdgcn_mfma_f32_32x32x16_bf16(k1, qf[c], S1, 0, 0, 0);
                }
                __builtin_amdgcn_s_setprio(0);

                // causal mask (diagonal-straddling step only)
                // k = kt*64 + t2*32 + (r&3) + 8*(r>>2) + 4*hi
                if (kt * 64 + 63 > qrow0) {
                    #pragma unroll
                    for (int r = 0; r < 16; ++r) {
                        const int kl = kt * 64 + (r & 3) + 8 * (r >> 2) + 4 * hi;
                        if (kl > qglob)      S0[r] = -INFINITY;
                        if (kl + 32 > qglob) S1[r] = -INFINITY;
                    }
                }

                // row max: 31 in-lane + 1 cross-half shuffle
                float mt = S0[0];
                #pragma unroll
                for (int r = 1; r < 16; ++r) mt = fmaxf(mt, S0[r]);
                #pragma unroll
                for (int r = 0; r < 16; ++r) mt = fmaxf(mt, S1[r]);
                mt = fmaxf(mt, __shfl_xor(mt, 32));

                // defer-max (also handles first-tile init: alpha=exp2(-inf)=0)
                float lscale = 1.f;
                if (__any(mt > m + 64.f)) {
                    const float mn = fmaxf(m, mt);
                    const float alpha = exp2f((m - mn) * S2);
                    m = mn; lscale = alpha;
                    #pragma unroll
                    for (int r = 0; r < 16; ++r) {
                        const int qloc = (r & 3) + 8 * (r >> 2) + 4 * hi;
                        const float ar = __shfl(alpha, qloc);
                        O0[r] *= ar; O1[r] *= ar;
                    }
                }

                // P = exp2((S-m)*S2), pack to bf16 words in-register
                float lt = 0.f;
                u32 w0[8], w1[8];
                #pragma unroll
                for (int i = 0; i < 8; ++i) {
                    const float p0 = exp2f((S0[2 * i]     - m) * S2);
                    const float p1 = exp2f((S0[2 * i + 1] - m) * S2);
                    const float p2 = exp2f((S1[2 * i]     - m) * S2);
                    const float p3 = exp2f((S1[2 * i + 1] - m) * S2);
                    lt += (p0 + p1) + (p2 + p3);
                    w0[i] = cvtpk(p0, p1);
                    w1[i] = cvtpk(p2, p3);
                }
                lt += __shfl_xor(lt, 32);
                ls = ls * lscale + lt;

                // O += P @ V : assemble A-frags via permlane32_swap, B from Vs
                __builtin_amdgcn_s_setprio(1);
                #pragma unroll
                for (int t2 = 0; t2 < 2; ++t2) {
                    #pragma unroll
                    for (int c1 = 0; c1 < 2; ++c1) {
                        u32 a0 = t2 ? w1[4 * c1 + 0] : w0[4 * c1 + 0];
                        u32 b0 = t2 ? w1[4 * c1 + 2] : w0[4 * c1 + 2];
                        u32 a1 = t2 ? w1[4 * c1 + 1] : w0[4 * c1 + 1];
                        u32 b1 = t2 ? w1[4 * c1 + 3] : w0[4 * c1 + 3];
                        pswap(a0, b0);   // -> frag words 0 and 2
                        pswap(a1, b1);   // -> frag words 1 and 3
                        u32x4 fr; fr.x = a0; fr.y = a1; fr.z = b0; fr.w = b1;
                        const bf16x8 pf = __builtin_bit_cast(bf16x8, fr);
                        const int c = t2 * 2 + c1;
                        const int co = ((2 * c + hi) ^ rsw8) << 3;
                        const bf16x8 v0 = *(const bf16x8*)&Vc[q31 * 64 + co];
                        const bf16x8 v1 = *(const bf16x8*)&Vc[(32 + q31) * 64 + co];
                        O0 = __builtin_amdgcn_mfma_f32_32x32x16_bf16(pf, v0, O0, 0, 0, 0);
                        O1 = __builtin_amdgcn_mfma_f32_32x32x16_bf16(pf, v1, O1, 0, 0, 0);
                    }
                }
                __builtin_amdgcn_s_setprio(0);
            }

            __syncthreads();  // drains DMA (vmcnt) + all waves done with buf
            cur ^= 1;
        }

        // epilogue: O row r -> q = qrow0 + (r&3)+8*(r>>2)+4*hi, col = d
        #pragma unroll
        for (int r = 0; r < 16; ++r) {
            const int qloc = (r & 3) + 8 * (r >> 2) + 4 * hi;
            const float inv = __builtin_amdgcn_rcpf(__shfl(ls, qloc));
            u16* yp = yb + (size_t)(b * Tn + qrow0 + qloc) * Cn + h * HDn + q31;
            yp[0]  = f2b(O0[r] * inv);
            yp[32] = f2b(O1[r] * inv);
        }
    }
}

// ---------------------------------------------------------------------------
extern "C" void kernel_launch(void* const* d_in, const int* in_sizes, int n_in,
                              void* d_out, int out_size, void* d_ws, size_t ws_size,
                              hipStream_t stream)
{
    const float* x      = (const float*)d_in[0];
    const float* W_attn = (const float*)d_in[1];
    const float* b_attn = (const float*)d_in[2];
    const float* W_proj = (const float*)d_in[3];
    const float* b_proj = (const float*)d_in[4];
    float* out = (float*)d_out;

    // Workspace (bf16): xb | WaT | WpT | qkvb | yb | vT  (~108 MB)
    u16* xb   = (u16*)d_ws;
    u16* WaT  = xb   + (size_t)Mn * Cn;
    u16* WpT  = WaT  + (size_t)3 * Cn * Cn;
    u16* qkvb = WpT  + (size_t)Cn * Cn;
    u16* yb   = qkvb + (size_t)Mn * 3 * Cn;
    u16* vT   = yb   + (size_t)Mn * Cn;

    cvt_f32_bf16_kernel<<<(Mn * Cn / 4 + 255) / 256, 256, 0, stream>>>(
        (const float4*)x, (ushort4*)xb, Mn * Cn / 4);

    transpose_cvt_kernel<<<dim3(3 * Cn / 32, Cn / 32), 256, 0, stream>>>(
        W_attn, WaT, Cn, 3 * Cn);
    transpose_cvt_kernel<<<dim3(Cn / 32, Cn / 32), 256, 0, stream>>>(
        W_proj, WpT, Cn, Cn);

    // qkv = x @ W_attn + b_attn; Q/K -> qkvb rows, V -> vT (fused transpose)
    gemm_bf16_kernel<true, true><<<24 * 64, 256, 0, stream>>>(
        xb, WaT, b_attn, qkvb, nullptr, vT, 3 * Cn, Cn, 24);

    // causal MFMA attention -> yb (bf16); grid 512, XCD-grouped
    attn_mfma6_kernel<<<512, 256, 0, stream>>>(qkvb, vT, yb);

    // out = y @ W_proj + b_proj (f32 out)
    gemm_bf16_kernel<false, false><<<8 * 64, 256, 0, stream>>>(
        yb, WpT, b_proj, nullptr, out, nullptr, Cn, Cn, 8);
}

// Round 9
// 200.669 us; speedup vs baseline: 1.1995x; 1.0088x over previous
//
#include <hip/hip_runtime.h>
#include <math.h>

// Problem constants
#define Bn 4
#define Tn 2048
#define Cn 1024
#define Hn 16
#define HDn 64
#define Mn (Bn * Tn)  // 8192 tokens

typedef unsigned short u16;
typedef unsigned int u32;
typedef __attribute__((ext_vector_type(8))) short bf16x8;        // 8 bf16 = 4 VGPRs
typedef __attribute__((ext_vector_type(8))) unsigned short us8;  // 16B chunk
typedef __attribute__((ext_vector_type(4))) float f32x4;         // 16x16 MFMA acc
typedef __attribute__((ext_vector_type(16))) float f32x16;       // 32x32 MFMA acc
typedef __attribute__((ext_vector_type(4))) unsigned int u32x4;

__device__ __forceinline__ float b2f(u16 u) {
    return __uint_as_float(((u32)u) << 16);
}
__device__ __forceinline__ u16 f2b(float f) {
    u32 u = __float_as_uint(f);
    return (u16)((u + 0x7FFFu + ((u >> 16) & 1u)) >> 16);  // RNE
}
__device__ __forceinline__ u32 cvtpk(float a, float b) {   // {lo:bf16(a), hi:bf16(b)}
    u32 d;
    asm("v_cvt_pk_bf16_f32 %0, %1, %2" : "=v"(d) : "v"(a), "v"(b));
    return d;
}
// v_permlane32_swap_b32: a[32..63] <-> b[0..31]
__device__ __forceinline__ void pswap(u32& a, u32& b) {
    asm("v_permlane32_swap_b32 %0, %1" : "+v"(a), "+v"(b));
}

// XCD-grouped work id from flat block id (requires gridDim.x % 8 == 0).
__device__ __forceinline__ int xcd_work(int bid, int nwg) {
    return (bid & 7) * (nwg >> 3) + (bid >> 3);
}

// global_load_lds, width 16 (literal size required)
#define GLL(srcp, dstp)                                                     \
    __builtin_amdgcn_global_load_lds(                                       \
        (const __attribute__((address_space(1))) u32*)(srcp),               \
        (__attribute__((address_space(3))) u32*)(dstp), 16, 0, 0)

// ---------------------------------------------------------------------------
// fp32 -> bf16 elementwise convert (grid-stride, 2048 blocks)
// ---------------------------------------------------------------------------
__global__ __launch_bounds__(256) void cvt_f32_bf16_kernel(
    const float4* __restrict__ in, ushort4* __restrict__ out, int n4)
{
    for (int i = blockIdx.x * 256 + threadIdx.x; i < n4; i += gridDim.x * 256) {
        float4 v = in[i];
        ushort4 o;
        o.x = f2b(v.x); o.y = f2b(v.y); o.z = f2b(v.z); o.w = f2b(v.w);
        out[i] = o;
    }
}

// ---------------------------------------------------------------------------
// Transpose + convert: in [R,Cc] fp32 -> out [Cc,R] bf16. 32x32 LDS tiles.
// ---------------------------------------------------------------------------
__global__ __launch_bounds__(256) void transpose_cvt_kernel(
    const float* __restrict__ in, u16* __restrict__ out, int R, int Cc)
{
    __shared__ u16 t[32][33];
    const int c0 = blockIdx.x * 32, r0 = blockIdx.y * 32;
    const int tx = threadIdx.x & 31, ty = threadIdx.x >> 5;  // 32 x 8
    #pragma unroll
    for (int i = 0; i < 32; i += 8)
        t[ty + i][tx] = f2b(in[(size_t)(r0 + ty + i) * Cc + c0 + tx]);
    __syncthreads();
    #pragma unroll
    for (int i = 0; i < 32; i += 8)
        out[(size_t)(c0 + ty + i) * R + r0 + tx] = t[tx][ty + i];
}

// ---------------------------------------------------------------------------
// bf16 MFMA GEMM v2: Out[M,N] = A[M,K] @ BT[N,K]^T + bias[N]
// 128x128 tile, BK=32, 4 waves. T3 minimum 2-phase: double-buffered LDS,
// stage(next) issued BEFORE compute(cur), ONE __syncthreads per K-step
// (its implicit vmcnt(0) lands after the MFMA phase -> DMA latency hidden).
// QKV_MODE: output cols >= 2048 (V section) written transposed to vT[b][c][t].
// ---------------------------------------------------------------------------
template <bool OUT_BF16, bool QKV_MODE>
__global__ __launch_bounds__(256) void gemm_bf16_kernel(
    const u16* __restrict__ A, const u16* __restrict__ BT,
    const float* __restrict__ bias,
    u16* __restrict__ outb, float* __restrict__ outf, u16* __restrict__ vTout,
    int N, int K, int nx)
{
    __shared__ u16 Al[2][128 * 32];
    __shared__ u16 Bl[2][128 * 32];

    const int tid = threadIdx.x;
    const int workid = xcd_work(blockIdx.x, gridDim.x);
    const int brow = (workid / nx) * 128;
    const int bcol = (workid % nx) * 128;
    const int w  = tid >> 6;
    const int wr = w >> 1, wc = w & 1;
    const int l  = tid & 63;
    const int lr = l & 15;
    const int lk = (l >> 4) << 3;

    // staging geometry: chunk c = i*256+tid -> row=c>>2, col=(c&3)*8;
    // LDS dest = wave-uniform base + lane*16B (linear layout requirement)
    const int r0s = tid >> 2,            c0s = (tid & 3) << 3;
    const int r1s = (256 + tid) >> 2,    c1s = c0s;
    const int d0s = (tid & 192) * 8;
    const int d1s = (256 + (tid & 192)) * 8;

    f32x4 acc[4][4];
    #pragma unroll
    for (int m = 0; m < 4; ++m)
        #pragma unroll
        for (int n = 0; n < 4; ++n) acc[m][n] = (f32x4){0.f, 0.f, 0.f, 0.f};

    // prologue: stage k0=0 into buf 0
    GLL(&A [(size_t)(brow + r0s) * K + c0s], &Al[0][d0s]);
    GLL(&BT[(size_t)(bcol + r0s) * K + c0s], &Bl[0][d0s]);
    GLL(&A [(size_t)(brow + r1s) * K + c1s], &Al[0][d1s]);
    GLL(&BT[(size_t)(bcol + r1s) * K + c1s], &Bl[0][d1s]);
    __syncthreads();

    int cur = 0;
    for (int k0 = 0; k0 < K; k0 += 32) {
        // issue next tile's DMA first (lands during this tile's compute)
        if (k0 + 32 < K) {
            const int kn = k0 + 32;
            GLL(&A [(size_t)(brow + r0s) * K + kn + c0s], &Al[cur ^ 1][d0s]);
            GLL(&BT[(size_t)(bcol + r0s) * K + kn + c0s], &Bl[cur ^ 1][d0s]);
            GLL(&A [(size_t)(brow + r1s) * K + kn + c1s], &Al[cur ^ 1][d1s]);
            GLL(&BT[(size_t)(bcol + r1s) * K + kn + c1s], &Bl[cur ^ 1][d1s]);
        }

        bf16x8 a[4], b[4];
        #pragma unroll
        for (int m = 0; m < 4; ++m)
            a[m] = *(const bf16x8*)&Al[cur][(wr * 64 + m * 16 + lr) * 32 + lk];
        #pragma unroll
        for (int n = 0; n < 4; ++n)
            b[n] = *(const bf16x8*)&Bl[cur][(wc * 64 + n * 16 + lr) * 32 + lk];

        __builtin_amdgcn_s_setprio(1);
        #pragma unroll
        for (int m = 0; m < 4; ++m)
            #pragma unroll
            for (int n = 0; n < 4; ++n)
                acc[m][n] = __builtin_amdgcn_mfma_f32_16x16x32_bf16(
                    a[m], b[n], acc[m][n], 0, 0, 0);
        __builtin_amdgcn_s_setprio(0);

        __syncthreads();   // drains vmcnt(0)+lgkmcnt(0): next buf ready, cur free
        cur ^= 1;
    }

    // Epilogue. C/D layout: col = lane&15, row = (lane>>4)*4 + reg.
    const int orow0 = brow + wr * 64 + ((l >> 4) << 2);
    const int ocol0 = bcol + wc * 64 + lr;
    if (QKV_MODE && bcol >= 2048) {
        #pragma unroll
        for (int n = 0; n < 4; ++n) {
            const int c = ocol0 + n * 16 - 2048;
            const float bv = bias[ocol0 + n * 16];
            #pragma unroll
            for (int m = 0; m < 4; ++m) {
                const int row0 = orow0 + m * 16;
                const int bb = row0 >> 11, t0 = row0 & 2047;
                ushort4 pk;
                pk.x = f2b(acc[m][n][0] + bv);
                pk.y = f2b(acc[m][n][1] + bv);
                pk.z = f2b(acc[m][n][2] + bv);
                pk.w = f2b(acc[m][n][3] + bv);
                *(ushort4*)&vTout[((size_t)bb * Cn + c) * Tn + t0] = pk;
            }
        }
    } else {
        #pragma unroll
        for (int n = 0; n < 4; ++n) {
            const int col = ocol0 + n * 16;
            const float bv = bias[col];
            #pragma unroll
            for (int m = 0; m < 4; ++m) {
                #pragma unroll
                for (int r = 0; r < 4; ++r) {
                    const int row = orow0 + m * 16 + r;
                    const float v = acc[m][n][r] + bv;
                    if (OUT_BF16) outb[(size_t)row * N + col] = f2b(v);
                    else          outf[(size_t)row * N + col] = v;
                }
            }
        }
    }
}

// ---------------------------------------------------------------------------
// MFMA flash attention v6 (causal) - 32x32 MFMA, in-register softmax (T12).
// (unchanged from round 8 - verified)
// ---------------------------------------------------------------------------
__global__ __launch_bounds__(256, 2) void attn_mfma6_kernel(
    const u16* __restrict__ qkvb, const u16* __restrict__ vT,
    u16* __restrict__ yb)
{
    __shared__ u16 Kb[2][64 * 64];   // [k-row][d-chunk swizzled]
    __shared__ u16 Vb[2][64 * 64];   // [d-row][k-chunk swizzled]

    const int tid = threadIdx.x;
    const int w   = tid >> 6;        // wave 0..3
    const int l   = tid & 63;
    const int q31 = l & 31;          // q (QK^T B-col) / d (PV B-col)
    const int hi  = l >> 5;
    const int work = xcd_work(blockIdx.x, 512);
    const int pr  = work & 7;        // pair index 0..7
    const int bh  = work >> 3;       // 8 bh per XCD
    const int b   = bh >> 4, h = bh & 15;

    const float S2 = 0.18033688f;    // 0.125 * log2(e)

    const u16* Kg = qkvb + (size_t)(b * Tn) * (3 * Cn) + Cn + h * HDn;
    const u16* Vg = vT + (size_t)bh * HDn * Tn;

    const int srow = l >> 3;                   // staging row 0..7
    const int schk = ((l & 7) ^ srow) << 3;    // swizzled source chunk (u16)
    const int rloc = w * 16;                   // wave's staging row slice
    const int rsw8 = q31 & 7;                  // read-side XOR key (chunk idx)

    #pragma unroll 1
    for (int half = 0; half < 2; ++half) {
        const int qt = half ? (15 - pr) : pr;   // 128-row tile index
        const int ktmax = 2 * qt + 2;
        const int qrow0 = qt * 128 + w * 32;    // wave's first q row
        const int qglob = qrow0 + q31;          // this lane's q row

        // Q B-frags: qf[c] = Q[qglob][c*16 + hi*8 .. +7]
        const u16* Qp = qkvb + (size_t)(b * Tn + qglob) * (3 * Cn)
                        + h * HDn + hi * 8;
        bf16x8 qf[4];
        #pragma unroll
        for (int c = 0; c < 4; ++c) qf[c] = *(const bf16x8*)(Qp + c * 16);

        f32x16 O0, O1;
        #pragma unroll
        for (int r = 0; r < 16; ++r) { O0[r] = 0.f; O1[r] = 0.f; }
        float m = -INFINITY, ls = 0.f;

        // prologue: stage kt=0 into buf 0
        #pragma unroll
        for (int jc = 0; jc < 2; ++jc) {
            const int rr = rloc + jc * 8;
            GLL(Kg + (size_t)(rr + srow) * (3 * Cn) + schk, &Kb[0][rr * 64]);
            GLL(Vg + (size_t)(rr + srow) * Tn + schk,       &Vb[0][rr * 64]);
        }
        __syncthreads();

        int cur = 0;
        for (int kt = 0; kt < ktmax; ++kt) {
            if (kt + 1 < ktmax) {   // prefetch next tile into buf^1
                #pragma unroll
                for (int jc = 0; jc < 2; ++jc) {
                    const int rr = rloc + jc * 8;
                    GLL(Kg + (size_t)((kt + 1) * 64 + rr + srow) * (3 * Cn) + schk,
                        &Kb[cur ^ 1][rr * 64]);
                    GLL(Vg + (size_t)(rr + srow) * Tn + (kt + 1) * 64 + schk,
                        &Vb[cur ^ 1][rr * 64]);
                }
            }
            const u16* Kc = Kb[cur];
            const u16* Vc = Vb[cur];

            if (kt * 64 <= qrow0 + 31) {   // wave has unmasked work
                // S^T = K Q^T : two 32x32 tiles (k 0..31, 32..63)
                f32x16 S0, S1;
                #pragma unroll
                for (int r = 0; r < 16; ++r) { S0[r] = 0.f; S1[r] = 0.f; }
                __builtin_amdgcn_s_setprio(1);
                #pragma unroll
                for (int c = 0; c < 4; ++c) {
                    const int co = ((2 * c + hi) ^ rsw8) << 3;
                    const bf16x8 k0 = *(const bf16x8*)&Kc[q31 * 64 + co];
                    const bf16x8 k1 = *(const bf16x8*)&Kc[(32 + q31) * 64 + co];
                    S0 = __builtin_amdgcn_mfma_f32_32x32x16_bf16(k0, qf[c], S0, 0, 0, 0);
                    S1 = __builtin_amdgcn_mfma_f32_32x32x16_bf16(k1, qf[c], S1, 0, 0, 0);
                }
                __builtin_amdgcn_s_setprio(0);

                // causal mask (diagonal-straddling step only)
                if (kt * 64 + 63 > qrow0) {
                    #pragma unroll
                    for (int r = 0; r < 16; ++r) {
                        const int kl = kt * 64 + (r & 3) + 8 * (r >> 2) + 4 * hi;
                        if (kl > qglob)      S0[r] = -INFINITY;
                        if (kl + 32 > qglob) S1[r] = -INFINITY;
                    }
                }

                // row max: 31 in-lane + 1 cross-half shuffle
                float mt = S0[0];
                #pragma unroll
                for (int r = 1; r < 16; ++r) mt = fmaxf(mt, S0[r]);
                #pragma unroll
                for (int r = 0; r < 16; ++r) mt = fmaxf(mt, S1[r]);
                mt = fmaxf(mt, __shfl_xor(mt, 32));

                // defer-max (also handles first-tile init: alpha=exp2(-inf)=0)
                float lscale = 1.f;
                if (__any(mt > m + 64.f)) {
                    const float mn = fmaxf(m, mt);
                    const float alpha = exp2f((m - mn) * S2);
                    m = mn; lscale = alpha;
                    #pragma unroll
                    for (int r = 0; r < 16; ++r) {
                        const int qloc = (r & 3) + 8 * (r >> 2) + 4 * hi;
                        const float ar = __shfl(alpha, qloc);
                        O0[r] *= ar; O1[r] *= ar;
                    }
                }

                // P = exp2((S-m)*S2), pack to bf16 words in-register
                float lt = 0.f;
                u32 w0[8], w1[8];
                #pragma unroll
                for (int i = 0; i < 8; ++i) {
                    const float p0 = exp2f((S0[2 * i]     - m) * S2);
                    const float p1 = exp2f((S0[2 * i + 1] - m) * S2);
                    const float p2 = exp2f((S1[2 * i]     - m) * S2);
                    const float p3 = exp2f((S1[2 * i + 1] - m) * S2);
                    lt += (p0 + p1) + (p2 + p3);
                    w0[i] = cvtpk(p0, p1);
                    w1[i] = cvtpk(p2, p3);
                }
                lt += __shfl_xor(lt, 32);
                ls = ls * lscale + lt;

                // O += P @ V : assemble A-frags via permlane32_swap, B from Vs
                __builtin_amdgcn_s_setprio(1);
                #pragma unroll
                for (int t2 = 0; t2 < 2; ++t2) {
                    #pragma unroll
                    for (int c1 = 0; c1 < 2; ++c1) {
                        u32 a0 = t2 ? w1[4 * c1 + 0] : w0[4 * c1 + 0];
                        u32 b0 = t2 ? w1[4 * c1 + 2] : w0[4 * c1 + 2];
                        u32 a1 = t2 ? w1[4 * c1 + 1] : w0[4 * c1 + 1];
                        u32 b1 = t2 ? w1[4 * c1 + 3] : w0[4 * c1 + 3];
                        pswap(a0, b0);   // -> frag words 0 and 2
                        pswap(a1, b1);   // -> frag words 1 and 3
                        u32x4 fr; fr.x = a0; fr.y = a1; fr.z = b0; fr.w = b1;
                        const bf16x8 pf = __builtin_bit_cast(bf16x8, fr);
                        const int c = t2 * 2 + c1;
                        const int co = ((2 * c + hi) ^ rsw8) << 3;
                        const bf16x8 v0 = *(const bf16x8*)&Vc[q31 * 64 + co];
                        const bf16x8 v1 = *(const bf16x8*)&Vc[(32 + q31) * 64 + co];
                        O0 = __builtin_amdgcn_mfma_f32_32x32x16_bf16(pf, v0, O0, 0, 0, 0);
                        O1 = __builtin_amdgcn_mfma_f32_32x32x16_bf16(pf, v1, O1, 0, 0, 0);
                    }
                }
                __builtin_amdgcn_s_setprio(0);
            }

            __syncthreads();  // drains DMA (vmcnt) + all waves done with buf
            cur ^= 1;
        }

        // epilogue: O row r -> q = qrow0 + (r&3)+8*(r>>2)+4*hi, col = d
        #pragma unroll
        for (int r = 0; r < 16; ++r) {
            const int qloc = (r & 3) + 8 * (r >> 2) + 4 * hi;
            const float inv = __builtin_amdgcn_rcpf(__shfl(ls, qloc));
            u16* yp = yb + (size_t)(b * Tn + qrow0 + qloc) * Cn + h * HDn + q31;
            yp[0]  = f2b(O0[r] * inv);
            yp[32] = f2b(O1[r] * inv);
        }
    }
}

// ---------------------------------------------------------------------------
extern "C" void kernel_launch(void* const* d_in, const int* in_sizes, int n_in,
                              void* d_out, int out_size, void* d_ws, size_t ws_size,
                              hipStream_t stream)
{
    const float* x      = (const float*)d_in[0];
    const float* W_attn = (const float*)d_in[1];
    const float* b_attn = (const float*)d_in[2];
    const float* W_proj = (const float*)d_in[3];
    const float* b_proj = (const float*)d_in[4];
    float* out = (float*)d_out;

    // Workspace (bf16): xb | WaT | WpT | qkvb | yb | vT  (~108 MB)
    u16* xb   = (u16*)d_ws;
    u16* WaT  = xb   + (size_t)Mn * Cn;
    u16* WpT  = WaT  + (size_t)3 * Cn * Cn;
    u16* qkvb = WpT  + (size_t)Cn * Cn;
    u16* yb   = qkvb + (size_t)Mn * 3 * Cn;
    u16* vT   = yb   + (size_t)Mn * Cn;

    cvt_f32_bf16_kernel<<<2048, 256, 0, stream>>>(
        (const float4*)x, (ushort4*)xb, Mn * Cn / 4);

    transpose_cvt_kernel<<<dim3(3 * Cn / 32, Cn / 32), 256, 0, stream>>>(
        W_attn, WaT, Cn, 3 * Cn);
    transpose_cvt_kernel<<<dim3(Cn / 32, Cn / 32), 256, 0, stream>>>(
        W_proj, WpT, Cn, Cn);

    // qkv = x @ W_attn + b_attn; Q/K -> qkvb rows, V -> vT (fused transpose)
    gemm_bf16_kernel<true, true><<<24 * 64, 256, 0, stream>>>(
        xb, WaT, b_attn, qkvb, nullptr, vT, 3 * Cn, Cn, 24);

    // causal MFMA attention -> yb (bf16); grid 512, XCD-grouped
    attn_mfma6_kernel<<<512, 256, 0, stream>>>(qkvb, vT, yb);

    // out = y @ W_proj + b_proj (f32 out)
    gemm_bf16_kernel<false, false><<<8 * 64, 256, 0, stream>>>(
        yb, WpT, b_proj, nullptr, out, nullptr, Cn, Cn, 8);
}